// Round 1
// baseline (252.897 us; speedup 1.0000x reference)
//
#include <hip/hip_runtime.h>

typedef unsigned short u16;
typedef unsigned int u32;
typedef __bf16 bf16x8 __attribute__((ext_vector_type(8)));
typedef float f32x4 __attribute__((ext_vector_type(4)));

#define SEQ 2048
#define DMODEL 1024
#define NH 16
#define DK 64
#define BATCH 2
#define MTOT (BATCH * SEQ) // 4096

__device__ __forceinline__ u16 f2b(float f) {
  u32 u = __float_as_uint(f);
  u += 0x7fffu + ((u >> 16) & 1u);
  return (u16)(u >> 16);
}

__device__ __forceinline__ void gload16(const void* g, void* l) {
  __builtin_amdgcn_global_load_lds((const __attribute__((address_space(1))) u32*)g,
                                   (__attribute__((address_space(3))) u32*)l, 16, 0, 0);
}

// ---------------- fp32 -> bf16 convert (vectorized) ----------------
__global__ __launch_bounds__(256) void cvt_bf16(const float* __restrict__ in,
                                                u16* __restrict__ out, int n4) {
  int i = blockIdx.x * 256 + threadIdx.x;
  if (i < n4) {
    float4 v = ((const float4*)in)[i];
    uint2 o;
    o.x = (u32)f2b(v.x) | ((u32)f2b(v.y) << 16);
    o.y = (u32)f2b(v.z) | ((u32)f2b(v.w) << 16);
    ((uint2*)out)[i] = o;
  }
}

// ---------------- Wo transpose + convert: wot[e][d] = wo[d][e] ----------------
__global__ __launch_bounds__(256) void transpose_wo(const float* __restrict__ wo,
                                                    u16* __restrict__ wot) {
  __shared__ float tile[32][33];
  const int bx = blockIdx.x * 32; // e block
  const int by = blockIdx.y * 32; // d block
  const int tx = threadIdx.x & 31, ty = threadIdx.x >> 5;
  for (int j = ty; j < 32; j += 8)
    tile[j][tx] = wo[(size_t)(by + j) * DMODEL + bx + tx];
  __syncthreads();
  for (int j = ty; j < 32; j += 8)
    wot[(size_t)(bx + j) * DMODEL + by + tx] = f2b(tile[tx][j]);
}

// ---------------- shared GEMM mainloop: C128x128 = A[M,K] * Bt[N,K]^T ----------------
__device__ __forceinline__ void gemm_core(const u16* __restrict__ A,
                                          const u16* __restrict__ Bt,
                                          int mbase, int nbase,
                                          u16* As, u16* Bs, f32x4 acc[4][4]) {
  const int t = threadIdx.x;
  const int lane = t & 63, w = t >> 6;
  const int wr = w >> 1, wc = w & 1;
  const int l15 = lane & 15, lg = lane >> 4;
  const int srow = t >> 2, scol = (t & 3) * 8;
  (void)lane;

  for (int kb = 0; kb < DMODEL; kb += 32) {
    gload16(&A[(size_t)(mbase + srow) * DMODEL + kb + scol], &As[t * 8]);
    gload16(&A[(size_t)(mbase + 64 + srow) * DMODEL + kb + scol], &As[2048 + t * 8]);
    gload16(&Bt[(size_t)(nbase + srow) * DMODEL + kb + scol], &Bs[t * 8]);
    gload16(&Bt[(size_t)(nbase + 64 + srow) * DMODEL + kb + scol], &Bs[2048 + t * 8]);
    __syncthreads();
    bf16x8 af[4], bfr[4];
#pragma unroll
    for (int mi = 0; mi < 4; ++mi)
      af[mi] = *(const bf16x8*)&As[(wr * 64 + mi * 16 + l15) * 32 + lg * 8];
#pragma unroll
    for (int ni = 0; ni < 4; ++ni)
      bfr[ni] = *(const bf16x8*)&Bs[(wc * 64 + ni * 16 + l15) * 32 + lg * 8];
#pragma unroll
    for (int mi = 0; mi < 4; ++mi)
#pragma unroll
      for (int ni = 0; ni < 4; ++ni)
        acc[mi][ni] = __builtin_amdgcn_mfma_f32_16x16x32_bf16(af[mi], bfr[ni], acc[mi][ni], 0, 0, 0);
    __syncthreads();
  }
}

// ---------------- fused QKV projection + RoPE epilogue ----------------
// grid: (M/128=32, 3*8=24). y>>3 = which matrix (0=Q,1=K,2=V), y&7 = n-tile.
// Output column c of X*W^T maps to head h=c%16, dim k=c/16 (split_heads layout).
// RoPE pair: (k=2i, k=2i+1) = columns (32i+h, 32i+16+h) -> adjacent ni fragments.
__global__ __launch_bounds__(256) void gemm_qkv(
    const u16* __restrict__ Xb, const u16* __restrict__ Wqb,
    const u16* __restrict__ Wkb, const u16* __restrict__ Wvb,
    u16* __restrict__ Qb, u16* __restrict__ Kb, u16* __restrict__ Vb,
    const int* __restrict__ tokpos) {
  __shared__ __align__(16) u16 As[128 * 32];
  __shared__ __align__(16) u16 Bs[128 * 32];

  const int mat = blockIdx.y >> 3;
  const int nbase = (blockIdx.y & 7) * 128;
  const int mbase = blockIdx.x * 128;
  const u16* Bt = (mat == 0) ? Wqb : ((mat == 1) ? Wkb : Wvb);

  f32x4 acc[4][4];
#pragma unroll
  for (int mi = 0; mi < 4; ++mi)
#pragma unroll
    for (int ni = 0; ni < 4; ++ni) {
      f32x4 z = {0.f, 0.f, 0.f, 0.f};
      acc[mi][ni] = z;
    }

  gemm_core(Xb, Bt, mbase, nbase, As, Bs, acc);

  const int t = threadIdx.x;
  const int lane = t & 63, w = t >> 6;
  const int wr = w >> 1, wc = w & 1;
  const int l15 = lane & 15, lg = lane >> 4;

  if (mat == 2) { // V: no rope, write [B,H,S,64]
#pragma unroll
    for (int mi = 0; mi < 4; ++mi) {
#pragma unroll
      for (int r = 0; r < 4; ++r) {
        const int row = mbase + wr * 64 + mi * 16 + lg * 4 + r;
        const int bi = row >> 11, s = row & (SEQ - 1);
#pragma unroll
        for (int ni = 0; ni < 4; ++ni) {
          const int c = nbase + wc * 64 + ni * 16 + l15;
          const int hh = c & 15, vd = c >> 4;
          Vb[((size_t)((bi * NH + hh) * SEQ + s) << 6) + vd] = f2b(acc[mi][ni][r]);
        }
      }
    }
  } else { // Q or K: rope on (ni, ni+1) pairs; h = l15, pair index Xi uniform per frag
    u16* Ob = (mat == 0) ? Qb : Kb;
#pragma unroll
    for (int ni = 0; ni < 4; ni += 2) {
      const int Xi = (nbase + wc * 64 + ni * 16) >> 5; // 0..31
      const float invf = powf(1000.0f, -(float)Xi / 32.0f);
#pragma unroll
      for (int mi = 0; mi < 4; ++mi) {
#pragma unroll
        for (int r = 0; r < 4; ++r) {
          const int row = mbase + wr * 64 + mi * 16 + lg * 4 + r;
          const int bi = row >> 11, s = row & (SEQ - 1);
          const float pos = (float)tokpos[s];
          const float ang = pos * invf;
          float sn, cs;
          sincosf(ang, &sn, &cs);
          const float x1 = acc[mi][ni][r], x2 = acc[mi][ni + 1][r];
          const float r1 = x1 * cs - x2 * sn;
          const float r2 = x1 * sn + x2 * cs;
          const u32 pk = (u32)f2b(r1) | ((u32)f2b(r2) << 16);
          *(u32*)&Ob[((size_t)((bi * NH + l15) * SEQ + s) << 6) + (Xi << 1)] = pk;
        }
      }
    }
  }
}

// ---------------- flash attention (causal, online softmax) ----------------
// grid: (S/64=32 q-tiles, B*H=32). block = 256 thr = 4 waves, wave owns 16 q rows.
__global__ __launch_bounds__(256) void flash_attn(
    const u16* __restrict__ Qg, const u16* __restrict__ Kg,
    const u16* __restrict__ Vg, u16* __restrict__ Ag) {
  __shared__ __align__(16) u16 Ks[64][72];
  __shared__ __align__(16) u16 Vt[64][72]; // V transposed: Vt[v][kv]
  __shared__ __align__(16) u16 Ps[4][16][72];

  const int qt = blockIdx.x;
  const int bh = blockIdx.y;
  const int b = bh >> 4, h = bh & 15;
  const int qbase = qt * 64;

  const size_t hoff = (size_t)bh * SEQ * DK;
  const u16* Qh = Qg + hoff;
  const u16* Kh = Kg + hoff;
  const u16* Vh = Vg + hoff;

  const int t = threadIdx.x;
  const int lane = t & 63, w = t >> 6;
  const int l15 = lane & 15, lg = lane >> 4;

  const int qrow = qbase + w * 16 + l15;
  const bf16x8 qf0 = *(const bf16x8*)&Qh[(size_t)qrow * DK + lg * 8];
  const bf16x8 qf1 = *(const bf16x8*)&Qh[(size_t)qrow * DK + 32 + lg * 8];

  f32x4 oacc[4];
  float m_r[4], l_r[4];
#pragma unroll
  for (int vf = 0; vf < 4; ++vf) {
    f32x4 z = {0.f, 0.f, 0.f, 0.f};
    oacc[vf] = z;
  }
#pragma unroll
  for (int r = 0; r < 4; ++r) {
    m_r[r] = -1e30f;
    l_r[r] = 0.0f;
  }

  const int sr = t >> 2, sc = (t & 3) * 16;

  for (int kt = 0; kt <= qt; ++kt) {
    const int kvbase = kt * 64;
    __syncthreads();
    // stage K rows (row-major, padded)
    *(uint4*)&Ks[sr][sc] = *(const uint4*)&Kh[(size_t)(kvbase + sr) * DK + sc];
    *(uint4*)&Ks[sr][sc + 8] = *(const uint4*)&Kh[(size_t)(kvbase + sr) * DK + sc + 8];
    // stage V transposed
    uint4 va = *(const uint4*)&Vh[(size_t)(kvbase + sr) * DK + sc];
    uint4 vb4 = *(const uint4*)&Vh[(size_t)(kvbase + sr) * DK + sc + 8];
    const u16* vav = (const u16*)&va;
    const u16* vbv = (const u16*)&vb4;
#pragma unroll
    for (int i = 0; i < 8; ++i) Vt[sc + i][sr] = vav[i];
#pragma unroll
    for (int i = 0; i < 8; ++i) Vt[sc + 8 + i][sr] = vbv[i];
    __syncthreads();

    // S = Q K^T  (16 q rows x 64 kv cols per wave)
    f32x4 sf[4];
#pragma unroll
    for (int f = 0; f < 4; ++f) {
      bf16x8 k0 = *(const bf16x8*)&Ks[f * 16 + l15][lg * 8];
      bf16x8 k1 = *(const bf16x8*)&Ks[f * 16 + l15][32 + lg * 8];
      f32x4 z = {0.f, 0.f, 0.f, 0.f};
      z = __builtin_amdgcn_mfma_f32_16x16x32_bf16(qf0, k0, z, 0, 0, 0);
      z = __builtin_amdgcn_mfma_f32_16x16x32_bf16(qf1, k1, z, 0, 0, 0);
      sf[f] = z;
    }
    // scale + causal mask + row max
    float pmax[4];
#pragma unroll
    for (int r = 0; r < 4; ++r) pmax[r] = -1e30f;
#pragma unroll
    for (int f = 0; f < 4; ++f) {
      const int kvc = kvbase + f * 16 + l15;
#pragma unroll
      for (int r = 0; r < 4; ++r) {
        const int qr = qbase + w * 16 + lg * 4 + r;
        float sv = sf[f][r] * 0.125f;
        sv = (kvc > qr) ? -1e30f : sv;
        sf[f][r] = sv;
        pmax[r] = fmaxf(pmax[r], sv);
      }
    }
#pragma unroll
    for (int r = 0; r < 4; ++r)
#pragma unroll
      for (int msk = 1; msk < 16; msk <<= 1)
        pmax[r] = fmaxf(pmax[r], __shfl_xor(pmax[r], msk));

    float alpha[4], rsum[4];
#pragma unroll
    for (int r = 0; r < 4; ++r) {
      const float mn = fmaxf(m_r[r], pmax[r]);
      alpha[r] = __expf(m_r[r] - mn);
      m_r[r] = mn;
      float s = 0.0f;
#pragma unroll
      for (int f = 0; f < 4; ++f) {
        const float p = __expf(sf[f][r] - mn);
        sf[f][r] = p;
        s += p;
      }
      rsum[r] = s;
    }
#pragma unroll
    for (int r = 0; r < 4; ++r) {
#pragma unroll
      for (int msk = 1; msk < 16; msk <<= 1)
        rsum[r] += __shfl_xor(rsum[r], msk);
      l_r[r] = l_r[r] * alpha[r] + rsum[r];
#pragma unroll
      for (int vf = 0; vf < 4; ++vf) oacc[vf][r] *= alpha[r];
    }
    // P -> LDS (re-layout for PV A-operand)
#pragma unroll
    for (int f = 0; f < 4; ++f)
#pragma unroll
      for (int r = 0; r < 4; ++r)
        Ps[w][lg * 4 + r][f * 16 + l15] = f2b(sf[f][r]);
    __syncthreads();
    // O += P V
#pragma unroll
    for (int c = 0; c < 2; ++c) {
      const bf16x8 pa = *(const bf16x8*)&Ps[w][l15][c * 32 + lg * 8];
#pragma unroll
      for (int vf = 0; vf < 4; ++vf) {
        const bf16x8 vv = *(const bf16x8*)&Vt[vf * 16 + l15][c * 32 + lg * 8];
        oacc[vf] = __builtin_amdgcn_mfma_f32_16x16x32_bf16(pa, vv, oacc[vf], 0, 0, 0);
      }
    }
  }

  // normalize + write [B,S,D] bf16, d = h*64 + v
#pragma unroll
  for (int r = 0; r < 4; ++r) {
    const float inv = 1.0f / l_r[r];
    const int q = qbase + w * 16 + lg * 4 + r;
    const size_t base = ((size_t)(b * SEQ + q)) * DMODEL + h * DK;
#pragma unroll
    for (int vf = 0; vf < 4; ++vf)
      Ag[base + vf * 16 + l15] = f2b(oacc[vf][r] * inv);
  }
}

// ---------------- output projection: d_out = Ab * Wot^T (fp32 out) ----------------
__global__ __launch_bounds__(256) void gemm_out(const u16* __restrict__ Ab,
                                                const u16* __restrict__ Wotb,
                                                float* __restrict__ Co) {
  __shared__ __align__(16) u16 As[128 * 32];
  __shared__ __align__(16) u16 Bs[128 * 32];
  const int mbase = blockIdx.x * 128, nbase = blockIdx.y * 128;

  f32x4 acc[4][4];
#pragma unroll
  for (int mi = 0; mi < 4; ++mi)
#pragma unroll
    for (int ni = 0; ni < 4; ++ni) {
      f32x4 z = {0.f, 0.f, 0.f, 0.f};
      acc[mi][ni] = z;
    }

  gemm_core(Ab, Wotb, mbase, nbase, As, Bs, acc);

  const int t = threadIdx.x;
  const int lane = t & 63, w = t >> 6;
  const int wr = w >> 1, wc = w & 1;
  const int l15 = lane & 15, lg = lane >> 4;
#pragma unroll
  for (int mi = 0; mi < 4; ++mi) {
#pragma unroll
    for (int r = 0; r < 4; ++r) {
      const int row = mbase + wr * 64 + mi * 16 + lg * 4 + r;
#pragma unroll
      for (int ni = 0; ni < 4; ++ni) {
        const int c = nbase + wc * 64 + ni * 16 + l15;
        Co[(size_t)row * DMODEL + c] = acc[mi][ni][r];
      }
    }
  }
}

extern "C" void kernel_launch(void* const* d_in, const int* in_sizes, int n_in,
                              void* d_out, int out_size, void* d_ws, size_t ws_size,
                              hipStream_t stream) {
  const float* X = (const float*)d_in[0];
  const float* Wq = (const float*)d_in[1];
  const float* Wk = (const float*)d_in[2];
  const float* Wv = (const float*)d_in[3];
  const float* Wo = (const float*)d_in[4];
  const int* tokpos = (const int*)d_in[5];
  float* out = (float*)d_out;

  u16* p = (u16*)d_ws;
  u16* Xb = p;   p += (size_t)MTOT * DMODEL;        // 4M el
  u16* Wqb = p;  p += (size_t)DMODEL * DMODEL;      // 1M el
  u16* Wkb = p;  p += (size_t)DMODEL * DMODEL;
  u16* Wvb = p;  p += (size_t)DMODEL * DMODEL;
  u16* Wotb = p; p += (size_t)DMODEL * DMODEL;
  u16* Qb = p;   p += (size_t)BATCH * NH * SEQ * DK; // 4M el
  u16* Kb = p;   p += (size_t)BATCH * NH * SEQ * DK;
  u16* Vb = p;   p += (size_t)BATCH * NH * SEQ * DK;
  u16* Ab = Xb; // X is dead after QKV projection; reuse for attention output

  cvt_bf16<<<4096, 256, 0, stream>>>(X, Xb, (MTOT * DMODEL) / 4);
  cvt_bf16<<<1024, 256, 0, stream>>>(Wq, Wqb, (DMODEL * DMODEL) / 4);
  cvt_bf16<<<1024, 256, 0, stream>>>(Wk, Wkb, (DMODEL * DMODEL) / 4);
  cvt_bf16<<<1024, 256, 0, stream>>>(Wv, Wvb, (DMODEL * DMODEL) / 4);
  transpose_wo<<<dim3(32, 32), 256, 0, stream>>>(Wo, Wotb);

  gemm_qkv<<<dim3(32, 24), 256, 0, stream>>>(Xb, Wqb, Wkb, Wvb, Qb, Kb, Vb, tokpos);
  flash_attn<<<dim3(32, 32), 256, 0, stream>>>(Qb, Kb, Vb, Ab);
  gemm_out<<<dim3(32, 8), 256, 0, stream>>>(Ab, Wotb, out);
}

// Round 2
// 221.592 us; speedup vs baseline: 1.1413x; 1.1413x over previous
//
#include <hip/hip_runtime.h>

typedef unsigned short u16;
typedef unsigned int u32;
typedef __bf16 bf16x8 __attribute__((ext_vector_type(8)));
typedef float f32x4 __attribute__((ext_vector_type(4)));

#define SEQ 2048
#define DMODEL 1024
#define NH 16
#define DK 64
#define BATCH 2
#define MTOT (BATCH * SEQ) // 4096

__device__ __forceinline__ u16 f2b(float f) {
  u32 u = __float_as_uint(f);
  u += 0x7fffu + ((u >> 16) & 1u);
  return (u16)(u >> 16);
}

__device__ __forceinline__ void gload16(const void* g, void* l) {
  __builtin_amdgcn_global_load_lds((const __attribute__((address_space(1))) u32*)g,
                                   (__attribute__((address_space(3))) u32*)l, 16, 0, 0);
}

// ---------------- fp32 -> bf16 convert (vectorized) ----------------
__global__ __launch_bounds__(256) void cvt_bf16(const float* __restrict__ in,
                                                u16* __restrict__ out, int n4) {
  int i = blockIdx.x * 256 + threadIdx.x;
  if (i < n4) {
    float4 v = ((const float4*)in)[i];
    uint2 o;
    o.x = (u32)f2b(v.x) | ((u32)f2b(v.y) << 16);
    o.y = (u32)f2b(v.z) | ((u32)f2b(v.w) << 16);
    ((uint2*)out)[i] = o;
  }
}

// ---------------- Wo transpose + convert: wot[e][d] = wo[d][e] ----------------
__global__ __launch_bounds__(256) void transpose_wo(const float* __restrict__ wo,
                                                    u16* __restrict__ wot) {
  __shared__ float tile[32][33];
  const int bx = blockIdx.x * 32; // e block
  const int by = blockIdx.y * 32; // d block
  const int tx = threadIdx.x & 31, ty = threadIdx.x >> 5;
  for (int j = ty; j < 32; j += 8)
    tile[j][tx] = wo[(size_t)(by + j) * DMODEL + bx + tx];
  __syncthreads();
  for (int j = ty; j < 32; j += 8)
    wot[(size_t)(bx + j) * DMODEL + by + tx] = f2b(tile[tx][j]);
}

// ---------------- shared GEMM mainloop: C128x128 = A[M,K] * Bt[N,K]^T ----------------
__device__ __forceinline__ void gemm_core(const u16* __restrict__ A,
                                          const u16* __restrict__ Bt,
                                          int mbase, int nbase,
                                          u16* As, u16* Bs, f32x4 acc[4][4]) {
  const int t = threadIdx.x;
  const int lane = t & 63, w = t >> 6;
  const int wr = w >> 1, wc = w & 1;
  const int l15 = lane & 15, lg = lane >> 4;
  const int srow = t >> 2, scol = (t & 3) * 8;
  (void)lane;

  for (int kb = 0; kb < DMODEL; kb += 32) {
    gload16(&A[(size_t)(mbase + srow) * DMODEL + kb + scol], &As[t * 8]);
    gload16(&A[(size_t)(mbase + 64 + srow) * DMODEL + kb + scol], &As[2048 + t * 8]);
    gload16(&Bt[(size_t)(nbase + srow) * DMODEL + kb + scol], &Bs[t * 8]);
    gload16(&Bt[(size_t)(nbase + 64 + srow) * DMODEL + kb + scol], &Bs[2048 + t * 8]);
    __syncthreads();
    bf16x8 af[4], bfr[4];
#pragma unroll
    for (int mi = 0; mi < 4; ++mi)
      af[mi] = *(const bf16x8*)&As[(wr * 64 + mi * 16 + l15) * 32 + lg * 8];
#pragma unroll
    for (int ni = 0; ni < 4; ++ni)
      bfr[ni] = *(const bf16x8*)&Bs[(wc * 64 + ni * 16 + l15) * 32 + lg * 8];
#pragma unroll
    for (int mi = 0; mi < 4; ++mi)
#pragma unroll
      for (int ni = 0; ni < 4; ++ni)
        acc[mi][ni] = __builtin_amdgcn_mfma_f32_16x16x32_bf16(af[mi], bfr[ni], acc[mi][ni], 0, 0, 0);
    __syncthreads();
  }
}

// ---------------- fused QKV projection + RoPE epilogue ----------------
// grid: (M/128=32, 3*8=24). y>>3 = which matrix (0=Q,1=K,2=V), y&7 = n-tile.
// Output column c of X*W^T maps to head h=c%16, dim k=c/16 (split_heads layout).
// RoPE pair: (k=2i, k=2i+1) = columns (32i+h, 32i+16+h) -> adjacent ni fragments.
// Q gets the 1/sqrt(dk)=0.125 attention scale folded in (exact pow2).
// V is written TRANSPOSED per head: Vb[(bh*DK + vd)*SEQ + s].
__global__ __launch_bounds__(256) void gemm_qkv(
    const u16* __restrict__ Xb, const u16* __restrict__ Wqb,
    const u16* __restrict__ Wkb, const u16* __restrict__ Wvb,
    u16* __restrict__ Qb, u16* __restrict__ Kb, u16* __restrict__ Vb,
    const int* __restrict__ tokpos) {
  __shared__ __align__(16) u16 As[128 * 32];
  __shared__ __align__(16) u16 Bs[128 * 32];

  const int mat = blockIdx.y >> 3;
  const int nbase = (blockIdx.y & 7) * 128;
  const int mbase = blockIdx.x * 128;
  const u16* Bt = (mat == 0) ? Wqb : ((mat == 1) ? Wkb : Wvb);

  f32x4 acc[4][4];
#pragma unroll
  for (int mi = 0; mi < 4; ++mi)
#pragma unroll
    for (int ni = 0; ni < 4; ++ni) {
      f32x4 z = {0.f, 0.f, 0.f, 0.f};
      acc[mi][ni] = z;
    }

  gemm_core(Xb, Bt, mbase, nbase, As, Bs, acc);

  const int t = threadIdx.x;
  const int lane = t & 63, w = t >> 6;
  const int wr = w >> 1, wc = w & 1;
  const int l15 = lane & 15, lg = lane >> 4;

  if (mat == 2) { // V: no rope, write V^T per head [B,H,64,S]
#pragma unroll
    for (int mi = 0; mi < 4; ++mi) {
#pragma unroll
      for (int r = 0; r < 4; ++r) {
        const int row = mbase + wr * 64 + mi * 16 + lg * 4 + r;
        const int bi = row >> 11, s = row & (SEQ - 1);
#pragma unroll
        for (int ni = 0; ni < 4; ++ni) {
          const int c = nbase + wc * 64 + ni * 16 + l15;
          const int hh = c & 15, vd = c >> 4;
          Vb[((size_t)((bi * NH + hh) * DK + vd)) * SEQ + s] = f2b(acc[mi][ni][r]);
        }
      }
    }
  } else { // Q or K: rope on (ni, ni+1) pairs; h = l15, pair index Xi uniform per frag
    u16* Ob = (mat == 0) ? Qb : Kb;
    const float qscale = (mat == 0) ? 0.125f : 1.0f;
#pragma unroll
    for (int ni = 0; ni < 4; ni += 2) {
      const int Xi = (nbase + wc * 64 + ni * 16) >> 5; // 0..31
      const float invf = powf(1000.0f, -(float)Xi / 32.0f);
#pragma unroll
      for (int mi = 0; mi < 4; ++mi) {
#pragma unroll
        for (int r = 0; r < 4; ++r) {
          const int row = mbase + wr * 64 + mi * 16 + lg * 4 + r;
          const int bi = row >> 11, s = row & (SEQ - 1);
          const float pos = (float)tokpos[s];
          const float ang = pos * invf;
          float sn, cs;
          sincosf(ang, &sn, &cs);
          const float x1 = acc[mi][ni][r], x2 = acc[mi][ni + 1][r];
          const float r1 = (x1 * cs - x2 * sn) * qscale;
          const float r2 = (x1 * sn + x2 * cs) * qscale;
          const u32 pk = (u32)f2b(r1) | ((u32)f2b(r2) << 16);
          *(u32*)&Ob[((size_t)((bi * NH + l15) * SEQ + s) << 6) + (Xi << 1)] = pk;
        }
      }
    }
  }
}

// ---------------- flash attention (causal, online softmax) ----------------
// grid: (S/128=16 q-tiles REVERSED, B*H=32). block = 512 thr = 8 waves,
// wave owns 16 q rows. KV tile = 64. V comes in pre-transposed [bh][vd][s].
__global__ __launch_bounds__(512) void flash_attn(
    const u16* __restrict__ Qg, const u16* __restrict__ Kg,
    const u16* __restrict__ VTg, u16* __restrict__ Ag) {
  __shared__ __align__(16) u16 Ks[64][72];
  __shared__ __align__(16) u16 Vt[64][72]; // Vt[vd][kv]
  __shared__ __align__(16) u16 Ps[8][16][72];

  const int qt = (int)gridDim.x - 1 - (int)blockIdx.x; // heavy blocks first
  const int bh = blockIdx.y;
  const int b = bh >> 4, h = bh & 15;
  const int qbase = qt * 128;

  const size_t hoff = (size_t)bh * SEQ * DK;
  const u16* Qh = Qg + hoff;
  const u16* Kh = Kg + hoff;
  const u16* VTh = VTg + hoff;

  const int t = threadIdx.x;
  const int lane = t & 63, w = t >> 6;
  const int l15 = lane & 15, lg = lane >> 4;

  const int qrow = qbase + w * 16 + l15;
  const bf16x8 qf0 = *(const bf16x8*)&Qh[(size_t)qrow * DK + lg * 8];
  const bf16x8 qf1 = *(const bf16x8*)&Qh[(size_t)qrow * DK + 32 + lg * 8];

  f32x4 oacc[4];
  float m_r[4], l_r[4];
#pragma unroll
  for (int vf = 0; vf < 4; ++vf) {
    f32x4 z = {0.f, 0.f, 0.f, 0.f};
    oacc[vf] = z;
  }
#pragma unroll
  for (int r = 0; r < 4; ++r) {
    m_r[r] = -1e30f;
    l_r[r] = 0.0f;
  }

  const int srow = t >> 3, scol = (t & 7) * 8; // 512-thread staging map
  const int ktmax = 2 * qt + 1;

  for (int kt = 0; kt <= ktmax; ++kt) {
    const int kvbase = kt * 64;
    __syncthreads(); // protect previous iteration's LDS reads
    *(uint4*)&Ks[srow][scol] = *(const uint4*)&Kh[(size_t)(kvbase + srow) * DK + scol];
    *(uint4*)&Vt[srow][scol] = *(const uint4*)&VTh[(size_t)srow * SEQ + kvbase + scol];
    __syncthreads();

    if (kvbase > qbase + w * 16 + 15) continue; // tile fully masked for this wave

    // S = Q K^T  (16 q rows x 64 kv cols per wave); scale pre-folded into Q
    f32x4 sf[4];
#pragma unroll
    for (int f = 0; f < 4; ++f) {
      bf16x8 k0 = *(const bf16x8*)&Ks[f * 16 + l15][lg * 8];
      bf16x8 k1 = *(const bf16x8*)&Ks[f * 16 + l15][32 + lg * 8];
      f32x4 z = {0.f, 0.f, 0.f, 0.f};
      z = __builtin_amdgcn_mfma_f32_16x16x32_bf16(qf0, k0, z, 0, 0, 0);
      z = __builtin_amdgcn_mfma_f32_16x16x32_bf16(qf1, k1, z, 0, 0, 0);
      sf[f] = z;
    }
    // causal mask + row max
    float pmax[4];
#pragma unroll
    for (int r = 0; r < 4; ++r) pmax[r] = -1e30f;
#pragma unroll
    for (int f = 0; f < 4; ++f) {
      const int kvc = kvbase + f * 16 + l15;
#pragma unroll
      for (int r = 0; r < 4; ++r) {
        const int qr = qbase + w * 16 + lg * 4 + r;
        float sv = sf[f][r];
        sv = (kvc > qr) ? -1e30f : sv;
        sf[f][r] = sv;
        pmax[r] = fmaxf(pmax[r], sv);
      }
    }
#pragma unroll
    for (int r = 0; r < 4; ++r)
#pragma unroll
      for (int msk = 1; msk < 16; msk <<= 1)
        pmax[r] = fmaxf(pmax[r], __shfl_xor(pmax[r], msk));

    float alpha[4], rsum[4];
#pragma unroll
    for (int r = 0; r < 4; ++r) {
      const float mn = fmaxf(m_r[r], pmax[r]);
      alpha[r] = __expf(m_r[r] - mn);
      m_r[r] = mn;
      float s = 0.0f;
#pragma unroll
      for (int f = 0; f < 4; ++f) {
        const float p = __expf(sf[f][r] - mn);
        sf[f][r] = p;
        s += p;
      }
      rsum[r] = s;
    }
#pragma unroll
    for (int r = 0; r < 4; ++r) {
#pragma unroll
      for (int msk = 1; msk < 16; msk <<= 1)
        rsum[r] += __shfl_xor(rsum[r], msk);
      l_r[r] = l_r[r] * alpha[r] + rsum[r];
#pragma unroll
      for (int vf = 0; vf < 4; ++vf) oacc[vf][r] *= alpha[r];
    }
    // P -> LDS (re-layout for PV A-operand; Ps[w] is wave-private, no barrier)
#pragma unroll
    for (int f = 0; f < 4; ++f)
#pragma unroll
      for (int r = 0; r < 4; ++r)
        Ps[w][lg * 4 + r][f * 16 + l15] = f2b(sf[f][r]);
    // O += P V
#pragma unroll
    for (int c = 0; c < 2; ++c) {
      const bf16x8 pa = *(const bf16x8*)&Ps[w][l15][c * 32 + lg * 8];
#pragma unroll
      for (int vf = 0; vf < 4; ++vf) {
        const bf16x8 vv = *(const bf16x8*)&Vt[vf * 16 + l15][c * 32 + lg * 8];
        oacc[vf] = __builtin_amdgcn_mfma_f32_16x16x32_bf16(pa, vv, oacc[vf], 0, 0, 0);
      }
    }
  }

  // normalize + write [B,S,D] bf16, d = h*64 + v
#pragma unroll
  for (int r = 0; r < 4; ++r) {
    const float inv = 1.0f / l_r[r];
    const int q = qbase + w * 16 + lg * 4 + r;
    const size_t base = ((size_t)(b * SEQ + q)) * DMODEL + h * DK;
#pragma unroll
    for (int vf = 0; vf < 4; ++vf)
      Ag[base + vf * 16 + l15] = f2b(oacc[vf][r] * inv);
  }
}

// ---------------- output projection: d_out = Ab * Wot^T (fp32 out) ----------------
__global__ __launch_bounds__(256) void gemm_out(const u16* __restrict__ Ab,
                                                const u16* __restrict__ Wotb,
                                                float* __restrict__ Co) {
  __shared__ __align__(16) u16 As[128 * 32];
  __shared__ __align__(16) u16 Bs[128 * 32];
  const int mbase = blockIdx.x * 128, nbase = blockIdx.y * 128;

  f32x4 acc[4][4];
#pragma unroll
  for (int mi = 0; mi < 4; ++mi)
#pragma unroll
    for (int ni = 0; ni < 4; ++ni) {
      f32x4 z = {0.f, 0.f, 0.f, 0.f};
      acc[mi][ni] = z;
    }

  gemm_core(Ab, Wotb, mbase, nbase, As, Bs, acc);

  const int t = threadIdx.x;
  const int lane = t & 63, w = t >> 6;
  const int wr = w >> 1, wc = w & 1;
  const int l15 = lane & 15, lg = lane >> 4;
#pragma unroll
  for (int mi = 0; mi < 4; ++mi) {
#pragma unroll
    for (int r = 0; r < 4; ++r) {
      const int row = mbase + wr * 64 + mi * 16 + lg * 4 + r;
#pragma unroll
      for (int ni = 0; ni < 4; ++ni) {
        const int c = nbase + wc * 64 + ni * 16 + l15;
        Co[(size_t)row * DMODEL + c] = acc[mi][ni][r];
      }
    }
  }
}

extern "C" void kernel_launch(void* const* d_in, const int* in_sizes, int n_in,
                              void* d_out, int out_size, void* d_ws, size_t ws_size,
                              hipStream_t stream) {
  const float* X = (const float*)d_in[0];
  const float* Wq = (const float*)d_in[1];
  const float* Wk = (const float*)d_in[2];
  const float* Wv = (const float*)d_in[3];
  const float* Wo = (const float*)d_in[4];
  const int* tokpos = (const int*)d_in[5];
  float* out = (float*)d_out;

  u16* p = (u16*)d_ws;
  u16* Xb = p;   p += (size_t)MTOT * DMODEL;        // 4M el
  u16* Wqb = p;  p += (size_t)DMODEL * DMODEL;      // 1M el
  u16* Wkb = p;  p += (size_t)DMODEL * DMODEL;
  u16* Wvb = p;  p += (size_t)DMODEL * DMODEL;
  u16* Wotb = p; p += (size_t)DMODEL * DMODEL;
  u16* Qb = p;   p += (size_t)BATCH * NH * SEQ * DK; // 4M el
  u16* Kb = p;   p += (size_t)BATCH * NH * SEQ * DK;
  u16* Vb = p;   p += (size_t)BATCH * NH * SEQ * DK; // holds V^T [bh][vd][s]
  u16* Ab = Xb; // X is dead after QKV projection; reuse for attention output

  cvt_bf16<<<4096, 256, 0, stream>>>(X, Xb, (MTOT * DMODEL) / 4);
  cvt_bf16<<<1024, 256, 0, stream>>>(Wq, Wqb, (DMODEL * DMODEL) / 4);
  cvt_bf16<<<1024, 256, 0, stream>>>(Wk, Wkb, (DMODEL * DMODEL) / 4);
  cvt_bf16<<<1024, 256, 0, stream>>>(Wv, Wvb, (DMODEL * DMODEL) / 4);
  transpose_wo<<<dim3(32, 32), 256, 0, stream>>>(Wo, Wotb);

  gemm_qkv<<<dim3(32, 24), 256, 0, stream>>>(Xb, Wqb, Wkb, Wvb, Qb, Kb, Vb, tokpos);
  flash_attn<<<dim3(16, 32), 512, 0, stream>>>(Qb, Kb, Vb, Ab);
  gemm_out<<<dim3(32, 8), 256, 0, stream>>>(Ab, Wotb, out);
}

// Round 3
// 201.882 us; speedup vs baseline: 1.2527x; 1.0976x over previous
//
#include <hip/hip_runtime.h>

typedef unsigned short u16;
typedef unsigned int u32;
typedef __bf16 bf16x8 __attribute__((ext_vector_type(8)));
typedef float f32x4 __attribute__((ext_vector_type(4)));

#define SEQ 2048
#define DMODEL 1024
#define NH 16
#define DK 64
#define BATCH 2
#define MTOT (BATCH * SEQ) // 4096

__device__ __forceinline__ u16 f2b(float f) {
  u32 u = __float_as_uint(f);
  u += 0x7fffu + ((u >> 16) & 1u);
  return (u16)(u >> 16);
}

__device__ __forceinline__ void gload16(const void* g, void* l) {
  __builtin_amdgcn_global_load_lds((const __attribute__((address_space(1))) u32*)g,
                                   (__attribute__((address_space(3))) u32*)l, 16, 0, 0);
}

// ---------------- fp32 -> bf16 convert (vectorized) ----------------
__global__ __launch_bounds__(256) void cvt_bf16(const float* __restrict__ in,
                                                u16* __restrict__ out, int n4) {
  int i = blockIdx.x * 256 + threadIdx.x;
  if (i < n4) {
    float4 v = ((const float4*)in)[i];
    uint2 o;
    o.x = (u32)f2b(v.x) | ((u32)f2b(v.y) << 16);
    o.y = (u32)f2b(v.z) | ((u32)f2b(v.w) << 16);
    ((uint2*)out)[i] = o;
  }
}

// ---------------- Wo transpose + convert: wot[e][d] = wo[d][e] ----------------
__global__ __launch_bounds__(256) void transpose_wo(const float* __restrict__ wo,
                                                    u16* __restrict__ wot) {
  __shared__ float tile[32][33];
  const int bx = blockIdx.x * 32; // e block
  const int by = blockIdx.y * 32; // d block
  const int tx = threadIdx.x & 31, ty = threadIdx.x >> 5;
  for (int j = ty; j < 32; j += 8)
    tile[j][tx] = wo[(size_t)(by + j) * DMODEL + bx + tx];
  __syncthreads();
  for (int j = ty; j < 32; j += 8)
    wot[(size_t)(bx + j) * DMODEL + by + tx] = f2b(tile[tx][j]);
}

// ---------------- shared GEMM mainloop: C128x128 = A[M,K] * Bt[N,K]^T ----------------
__device__ __forceinline__ void gemm_core(const u16* __restrict__ A,
                                          const u16* __restrict__ Bt,
                                          int mbase, int nbase,
                                          u16* As, u16* Bs, f32x4 acc[4][4]) {
  const int t = threadIdx.x;
  const int lane = t & 63, w = t >> 6;
  const int wr = w >> 1, wc = w & 1;
  const int l15 = lane & 15, lg = lane >> 4;
  const int srow = t >> 2, scol = (t & 3) * 8;
  (void)lane;

  for (int kb = 0; kb < DMODEL; kb += 32) {
    gload16(&A[(size_t)(mbase + srow) * DMODEL + kb + scol], &As[t * 8]);
    gload16(&A[(size_t)(mbase + 64 + srow) * DMODEL + kb + scol], &As[2048 + t * 8]);
    gload16(&Bt[(size_t)(nbase + srow) * DMODEL + kb + scol], &Bs[t * 8]);
    gload16(&Bt[(size_t)(nbase + 64 + srow) * DMODEL + kb + scol], &Bs[2048 + t * 8]);
    __syncthreads();
    bf16x8 af[4], bfr[4];
#pragma unroll
    for (int mi = 0; mi < 4; ++mi)
      af[mi] = *(const bf16x8*)&As[(wr * 64 + mi * 16 + l15) * 32 + lg * 8];
#pragma unroll
    for (int ni = 0; ni < 4; ++ni)
      bfr[ni] = *(const bf16x8*)&Bs[(wc * 64 + ni * 16 + l15) * 32 + lg * 8];
#pragma unroll
    for (int mi = 0; mi < 4; ++mi)
#pragma unroll
      for (int ni = 0; ni < 4; ++ni)
        acc[mi][ni] = __builtin_amdgcn_mfma_f32_16x16x32_bf16(af[mi], bfr[ni], acc[mi][ni], 0, 0, 0);
    __syncthreads();
  }
}

// ---------------- fused QKV projection + RoPE epilogue ----------------
// Q gets 0.125*log2(e) folded in (attention scale + exp2-domain softmax).
// V is written TRANSPOSED per head: Vb[(bh*DK + vd)*SEQ + s].
__global__ __launch_bounds__(256) void gemm_qkv(
    const u16* __restrict__ Xb, const u16* __restrict__ Wqb,
    const u16* __restrict__ Wkb, const u16* __restrict__ Wvb,
    u16* __restrict__ Qb, u16* __restrict__ Kb, u16* __restrict__ Vb,
    const int* __restrict__ tokpos) {
  __shared__ __align__(16) u16 As[128 * 32];
  __shared__ __align__(16) u16 Bs[128 * 32];

  const int mat = blockIdx.y >> 3;
  const int nbase = (blockIdx.y & 7) * 128;
  const int mbase = blockIdx.x * 128;
  const u16* Bt = (mat == 0) ? Wqb : ((mat == 1) ? Wkb : Wvb);

  f32x4 acc[4][4];
#pragma unroll
  for (int mi = 0; mi < 4; ++mi)
#pragma unroll
    for (int ni = 0; ni < 4; ++ni) {
      f32x4 z = {0.f, 0.f, 0.f, 0.f};
      acc[mi][ni] = z;
    }

  gemm_core(Xb, Bt, mbase, nbase, As, Bs, acc);

  const int t = threadIdx.x;
  const int lane = t & 63, w = t >> 6;
  const int wr = w >> 1, wc = w & 1;
  const int l15 = lane & 15, lg = lane >> 4;

  if (mat == 2) { // V: no rope, write V^T per head [B,H,64,S]
#pragma unroll
    for (int mi = 0; mi < 4; ++mi) {
#pragma unroll
      for (int r = 0; r < 4; ++r) {
        const int row = mbase + wr * 64 + mi * 16 + lg * 4 + r;
        const int bi = row >> 11, s = row & (SEQ - 1);
#pragma unroll
        for (int ni = 0; ni < 4; ++ni) {
          const int c = nbase + wc * 64 + ni * 16 + l15;
          const int hh = c & 15, vd = c >> 4;
          Vb[((size_t)((bi * NH + hh) * DK + vd)) * SEQ + s] = f2b(acc[mi][ni][r]);
        }
      }
    }
  } else { // Q or K: rope on (ni, ni+1) pairs
    u16* Ob = (mat == 0) ? Qb : Kb;
    const float qscale = (mat == 0) ? 0.125f * 1.44269504088896f : 1.0f;
#pragma unroll
    for (int ni = 0; ni < 4; ni += 2) {
      const int Xi = (nbase + wc * 64 + ni * 16) >> 5; // 0..31
      const float invf = powf(1000.0f, -(float)Xi / 32.0f);
#pragma unroll
      for (int mi = 0; mi < 4; ++mi) {
#pragma unroll
        for (int r = 0; r < 4; ++r) {
          const int row = mbase + wr * 64 + mi * 16 + lg * 4 + r;
          const int bi = row >> 11, s = row & (SEQ - 1);
          const float pos = (float)tokpos[s];
          const float ang = pos * invf;
          float sn, cs;
          sincosf(ang, &sn, &cs);
          const float x1 = acc[mi][ni][r], x2 = acc[mi][ni + 1][r];
          const float r1 = (x1 * cs - x2 * sn) * qscale;
          const float r2 = (x1 * sn + x2 * cs) * qscale;
          const u32 pk = (u32)f2b(r1) | ((u32)f2b(r2) << 16);
          *(u32*)&Ob[((size_t)((bi * NH + l15) * SEQ + s) << 6) + (Xi << 1)] = pk;
        }
      }
    }
  }
}

// ---------------- flash attention (causal, online softmax, exp2-domain) ----------
// grid: (S/128=16 q-tiles REVERSED, B*H=32). 512 thr = 8 waves, wave owns 16 q rows.
// KV tile 64, double-buffered, staged by global_load_lds with XOR chunk swizzle:
// stored LDS[row][c] = global[row][c ^ (row&7)] (16B chunks), read with same XOR.
// V^T buffer has 80 rows; row 64 = ones => PV MFMA also accumulates softmax denom.
__global__ __launch_bounds__(512) void flash_attn(
    const u16* __restrict__ Qg, const u16* __restrict__ Kg,
    const u16* __restrict__ VTg, u16* __restrict__ Ag) {
  __shared__ __align__(16) u16 Ks[2][64 * 64];
  __shared__ __align__(16) u16 Vs[2][80 * 64];
  __shared__ __align__(16) u16 Ps[8][16][72];

  const int qt = (int)gridDim.x - 1 - (int)blockIdx.x; // heavy blocks first
  const int bh = blockIdx.y;
  const int b = bh >> 4, h = bh & 15;
  const int qbase = qt * 128;

  const size_t hoff = (size_t)bh * SEQ * DK;
  const u16* Qh = Qg + hoff;
  const u16* Kh = Kg + hoff;
  const u16* VTh = VTg + hoff;

  const int t = threadIdx.x;
  const int lane = t & 63, w = t >> 6;
  const int l15 = lane & 15, lg = lane >> 4;
  const int sw = l15 & 7; // read-side XOR

  // ones/zero rows of Vs (rows 64..79 of both buffers), swizzle-invariant
  for (int i = t; i < 2 * 16 * 64; i += 512) {
    const int bufi = i >> 10, rr = (i >> 6) & 15, cc = i & 63;
    Vs[bufi][(64 + rr) * 64 + cc] = (rr == 0) ? (u16)0x3F80 : (u16)0;
  }

  const int qrow = qbase + w * 16 + l15;
  const bf16x8 qf0 = *(const bf16x8*)&Qh[(size_t)qrow * DK + lg * 8];
  const bf16x8 qf1 = *(const bf16x8*)&Qh[(size_t)qrow * DK + 32 + lg * 8];

  f32x4 oacc[5];
  float m_r[4];
#pragma unroll
  for (int vf = 0; vf < 5; ++vf) {
    f32x4 z = {0.f, 0.f, 0.f, 0.f};
    oacc[vf] = z;
  }
#pragma unroll
  for (int r = 0; r < 4; ++r) m_r[r] = -1e30f;

  // staging map: thread t -> LDS linear bytes [t*16, t*16+16) = row t>>3, chunk t&7
  const int srow = t >> 3;                    // 0..63
  const int schunk = (t & 7) ^ (srow & 7);    // swizzled global source chunk

  const int ktmax = 2 * qt + 1;

  // prologue: stage tile 0 into buf 0
  gload16(&Kh[(size_t)srow * DK + schunk * 8], &Ks[0][t * 8]);
  gload16(&VTh[(size_t)srow * SEQ + schunk * 8], &Vs[0][t * 8]);

  for (int kt = 0; kt <= ktmax; ++kt) {
    const int buf = kt & 1;
    __syncthreads(); // tile kt landed; previous iteration's LDS reads done
    if (kt < ktmax) {
      const int nb = kt + 1;
      gload16(&Kh[(size_t)(nb * 64 + srow) * DK + schunk * 8], &Ks[buf ^ 1][t * 8]);
      gload16(&VTh[(size_t)srow * SEQ + nb * 64 + schunk * 8], &Vs[buf ^ 1][t * 8]);
    }
    const int kvbase = kt * 64;
    if (kvbase > qbase + w * 16 + 15) continue; // fully masked for this wave

    // S = Q K^T (scale+log2e pre-folded into Q)
    f32x4 sf[4];
#pragma unroll
    for (int f = 0; f < 4; ++f) {
      const int row = f * 16 + l15;
      bf16x8 k0 = *(const bf16x8*)&Ks[buf][row * 64 + (lg ^ sw) * 8];
      bf16x8 k1 = *(const bf16x8*)&Ks[buf][row * 64 + ((4 + lg) ^ sw) * 8];
      f32x4 z = {0.f, 0.f, 0.f, 0.f};
      z = __builtin_amdgcn_mfma_f32_16x16x32_bf16(qf0, k0, z, 0, 0, 0);
      z = __builtin_amdgcn_mfma_f32_16x16x32_bf16(qf1, k1, z, 0, 0, 0);
      sf[f] = z;
    }

    // causal mask (boundary tiles only) + row max
    float pmax[4];
#pragma unroll
    for (int r = 0; r < 4; ++r) pmax[r] = -1e30f;
    if (kvbase + 63 > qbase + w * 16) { // wave-uniform: tile straddles diagonal
#pragma unroll
      for (int f = 0; f < 4; ++f) {
        const int kvc = kvbase + f * 16 + l15;
#pragma unroll
        for (int r = 0; r < 4; ++r) {
          const int qr = qbase + w * 16 + lg * 4 + r;
          float sv = sf[f][r];
          sv = (kvc > qr) ? -1e30f : sv;
          sf[f][r] = sv;
          pmax[r] = fmaxf(pmax[r], sv);
        }
      }
    } else {
#pragma unroll
      for (int f = 0; f < 4; ++f)
#pragma unroll
        for (int r = 0; r < 4; ++r) pmax[r] = fmaxf(pmax[r], sf[f][r]);
    }
#pragma unroll
    for (int r = 0; r < 4; ++r)
#pragma unroll
      for (int msk = 1; msk < 16; msk <<= 1)
        pmax[r] = fmaxf(pmax[r], __shfl_xor(pmax[r], msk));

    float alpha[4];
#pragma unroll
    for (int r = 0; r < 4; ++r) {
      const float mn = fmaxf(m_r[r], pmax[r]);
      alpha[r] = exp2f(m_r[r] - mn);
      m_r[r] = mn;
#pragma unroll
      for (int f = 0; f < 4; ++f) sf[f][r] = exp2f(sf[f][r] - mn);
    }
#pragma unroll
    for (int r = 0; r < 4; ++r)
#pragma unroll
      for (int vf = 0; vf < 5; ++vf) oacc[vf][r] *= alpha[r];

    // P -> LDS (wave-private re-layout for PV A-operand)
#pragma unroll
    for (int f = 0; f < 4; ++f)
#pragma unroll
      for (int r = 0; r < 4; ++r)
        Ps[w][lg * 4 + r][f * 16 + l15] = f2b(sf[f][r]);

    // O += P V (vf=4 accumulates the softmax denominator via ones row)
#pragma unroll
    for (int c = 0; c < 2; ++c) {
      const bf16x8 pa = *(const bf16x8*)&Ps[w][l15][c * 32 + lg * 8];
#pragma unroll
      for (int vf = 0; vf < 5; ++vf) {
        const bf16x8 vv =
            *(const bf16x8*)&Vs[buf][(vf * 16 + l15) * 64 + ((c * 4 + lg) ^ sw) * 8];
        oacc[vf] = __builtin_amdgcn_mfma_f32_16x16x32_bf16(pa, vv, oacc[vf], 0, 0, 0);
      }
    }
  }

  // l lives in oacc[4] at lanes with l15==0; broadcast within each 16-lane group
#pragma unroll
  for (int r = 0; r < 4; ++r) {
    const float l = __shfl(oacc[4][r], lg * 16);
    const float inv = 1.0f / l;
    const int q = qbase + w * 16 + lg * 4 + r;
    const size_t base = ((size_t)(b * SEQ + q)) * DMODEL + h * DK;
#pragma unroll
    for (int vf = 0; vf < 4; ++vf)
      Ag[base + vf * 16 + l15] = f2b(oacc[vf][r] * inv);
  }
}

// ---------------- output projection: d_out = Ab * Wot^T (fp32 out) ----------------
__global__ __launch_bounds__(256) void gemm_out(const u16* __restrict__ Ab,
                                                const u16* __restrict__ Wotb,
                                                float* __restrict__ Co) {
  __shared__ __align__(16) u16 As[128 * 32];
  __shared__ __align__(16) u16 Bs[128 * 32];
  const int mbase = blockIdx.x * 128, nbase = blockIdx.y * 128;

  f32x4 acc[4][4];
#pragma unroll
  for (int mi = 0; mi < 4; ++mi)
#pragma unroll
    for (int ni = 0; ni < 4; ++ni) {
      f32x4 z = {0.f, 0.f, 0.f, 0.f};
      acc[mi][ni] = z;
    }

  gemm_core(Ab, Wotb, mbase, nbase, As, Bs, acc);

  const int t = threadIdx.x;
  const int lane = t & 63, w = t >> 6;
  const int wr = w >> 1, wc = w & 1;
  const int l15 = lane & 15, lg = lane >> 4;
#pragma unroll
  for (int mi = 0; mi < 4; ++mi) {
#pragma unroll
    for (int r = 0; r < 4; ++r) {
      const int row = mbase + wr * 64 + mi * 16 + lg * 4 + r;
#pragma unroll
      for (int ni = 0; ni < 4; ++ni) {
        const int c = nbase + wc * 64 + ni * 16 + l15;
        Co[(size_t)row * DMODEL + c] = acc[mi][ni][r];
      }
    }
  }
}

extern "C" void kernel_launch(void* const* d_in, const int* in_sizes, int n_in,
                              void* d_out, int out_size, void* d_ws, size_t ws_size,
                              hipStream_t stream) {
  const float* X = (const float*)d_in[0];
  const float* Wq = (const float*)d_in[1];
  const float* Wk = (const float*)d_in[2];
  const float* Wv = (const float*)d_in[3];
  const float* Wo = (const float*)d_in[4];
  const int* tokpos = (const int*)d_in[5];
  float* out = (float*)d_out;

  u16* p = (u16*)d_ws;
  u16* Xb = p;   p += (size_t)MTOT * DMODEL;        // 4M el
  u16* Wqb = p;  p += (size_t)DMODEL * DMODEL;      // 1M el
  u16* Wkb = p;  p += (size_t)DMODEL * DMODEL;
  u16* Wvb = p;  p += (size_t)DMODEL * DMODEL;
  u16* Wotb = p; p += (size_t)DMODEL * DMODEL;
  u16* Qb = p;   p += (size_t)BATCH * NH * SEQ * DK; // 4M el
  u16* Kb = p;   p += (size_t)BATCH * NH * SEQ * DK;
  u16* Vb = p;   p += (size_t)BATCH * NH * SEQ * DK; // holds V^T [bh][vd][s]
  u16* Ab = Xb; // X is dead after QKV projection; reuse for attention output

  cvt_bf16<<<4096, 256, 0, stream>>>(X, Xb, (MTOT * DMODEL) / 4);
  cvt_bf16<<<1024, 256, 0, stream>>>(Wq, Wqb, (DMODEL * DMODEL) / 4);
  cvt_bf16<<<1024, 256, 0, stream>>>(Wk, Wkb, (DMODEL * DMODEL) / 4);
  cvt_bf16<<<1024, 256, 0, stream>>>(Wv, Wvb, (DMODEL * DMODEL) / 4);
  transpose_wo<<<dim3(32, 32), 256, 0, stream>>>(Wo, Wotb);

  gemm_qkv<<<dim3(32, 24), 256, 0, stream>>>(Xb, Wqb, Wkb, Wvb, Qb, Kb, Vb, tokpos);
  flash_attn<<<dim3(16, 32), 512, 0, stream>>>(Qb, Kb, Vb, Ab);
  gemm_out<<<dim3(32, 8), 256, 0, stream>>>(Ab, Wotb, out);
}

// Round 4
// 158.354 us; speedup vs baseline: 1.5970x; 1.2749x over previous
//
#include <hip/hip_runtime.h>

typedef unsigned short u16;
typedef unsigned int u32;
typedef __bf16 bf16x8 __attribute__((ext_vector_type(8)));
typedef float f32x4 __attribute__((ext_vector_type(4)));

#define SEQ 2048
#define DMODEL 1024
#define NH 16
#define DK 64
#define BATCH 2
#define MTOT (BATCH * SEQ) // 4096

__device__ __forceinline__ u16 f2b(float f) {
  u32 u = __float_as_uint(f);
  u += 0x7fffu + ((u >> 16) & 1u);
  return (u16)(u >> 16);
}

__device__ __forceinline__ void gload16(const void* g, void* l) {
  __builtin_amdgcn_global_load_lds((const __attribute__((address_space(1))) u32*)g,
                                   (__attribute__((address_space(3))) u32*)l, 16, 0, 0);
}

// ---------------- fp32 -> bf16 convert (vectorized) ----------------
__global__ __launch_bounds__(256) void cvt_bf16(const float* __restrict__ in,
                                                u16* __restrict__ out, int n4) {
  int i = blockIdx.x * 256 + threadIdx.x;
  if (i < n4) {
    float4 v = ((const float4*)in)[i];
    uint2 o;
    o.x = (u32)f2b(v.x) | ((u32)f2b(v.y) << 16);
    o.y = (u32)f2b(v.z) | ((u32)f2b(v.w) << 16);
    ((uint2*)out)[i] = o;
  }
}

// ---------------- Wo transpose + convert: wot[e][d] = wo[d][e] ----------------
__global__ __launch_bounds__(256) void transpose_wo(const float* __restrict__ wo,
                                                    u16* __restrict__ wot) {
  __shared__ float tile[32][33];
  const int bx = blockIdx.x * 32; // e block
  const int by = blockIdx.y * 32; // d block
  const int tx = threadIdx.x & 31, ty = threadIdx.x >> 5;
  for (int j = ty; j < 32; j += 8)
    tile[j][tx] = wo[(size_t)(by + j) * DMODEL + bx + tx];
  __syncthreads();
  for (int j = ty; j < 32; j += 8)
    wot[(size_t)(bx + j) * DMODEL + by + tx] = f2b(tile[tx][j]);
}

// ---------------- shared GEMM mainloop: C128x128 = A[M,K] * Bt[N,K]^T ----------------
__device__ __forceinline__ void gemm_core(const u16* __restrict__ A,
                                          const u16* __restrict__ Bt,
                                          int mbase, int nbase,
                                          u16* As, u16* Bs, f32x4 acc[4][4]) {
  const int t = threadIdx.x;
  const int lane = t & 63, w = t >> 6;
  const int wr = w >> 1, wc = w & 1;
  const int l15 = lane & 15, lg = lane >> 4;
  const int srow = t >> 2, scol = (t & 3) * 8;
  (void)lane;

  for (int kb = 0; kb < DMODEL; kb += 32) {
    gload16(&A[(size_t)(mbase + srow) * DMODEL + kb + scol], &As[t * 8]);
    gload16(&A[(size_t)(mbase + 64 + srow) * DMODEL + kb + scol], &As[2048 + t * 8]);
    gload16(&Bt[(size_t)(nbase + srow) * DMODEL + kb + scol], &Bs[t * 8]);
    gload16(&Bt[(size_t)(nbase + 64 + srow) * DMODEL + kb + scol], &Bs[2048 + t * 8]);
    __syncthreads();
    bf16x8 af[4], bfr[4];
#pragma unroll
    for (int mi = 0; mi < 4; ++mi)
      af[mi] = *(const bf16x8*)&As[(wr * 64 + mi * 16 + l15) * 32 + lg * 8];
#pragma unroll
    for (int ni = 0; ni < 4; ++ni)
      bfr[ni] = *(const bf16x8*)&Bs[(wc * 64 + ni * 16 + l15) * 32 + lg * 8];
#pragma unroll
    for (int mi = 0; mi < 4; ++mi)
#pragma unroll
      for (int ni = 0; ni < 4; ++ni)
        acc[mi][ni] = __builtin_amdgcn_mfma_f32_16x16x32_bf16(af[mi], bfr[ni], acc[mi][ni], 0, 0, 0);
    __syncthreads();
  }
}

// ---------------- fused QKV projection + RoPE epilogue ----------------
// Q gets 0.125*log2(e) folded in (attention scale + exp2-domain softmax).
// V is written TRANSPOSED per head: Vb[(bh*DK + vd)*SEQ + s].
__global__ __launch_bounds__(256) void gemm_qkv(
    const u16* __restrict__ Xb, const u16* __restrict__ Wqb,
    const u16* __restrict__ Wkb, const u16* __restrict__ Wvb,
    u16* __restrict__ Qb, u16* __restrict__ Kb, u16* __restrict__ Vb,
    const int* __restrict__ tokpos) {
  __shared__ __align__(16) u16 As[128 * 32];
  __shared__ __align__(16) u16 Bs[128 * 32];

  const int mat = blockIdx.y >> 3;
  const int nbase = (blockIdx.y & 7) * 128;
  const int mbase = blockIdx.x * 128;
  const u16* Bt = (mat == 0) ? Wqb : ((mat == 1) ? Wkb : Wvb);

  f32x4 acc[4][4];
#pragma unroll
  for (int mi = 0; mi < 4; ++mi)
#pragma unroll
    for (int ni = 0; ni < 4; ++ni) {
      f32x4 z = {0.f, 0.f, 0.f, 0.f};
      acc[mi][ni] = z;
    }

  gemm_core(Xb, Bt, mbase, nbase, As, Bs, acc);

  const int t = threadIdx.x;
  const int lane = t & 63, w = t >> 6;
  const int wr = w >> 1, wc = w & 1;
  const int l15 = lane & 15, lg = lane >> 4;

  if (mat == 2) { // V: no rope, write V^T per head [B,H,64,S]
#pragma unroll
    for (int mi = 0; mi < 4; ++mi) {
#pragma unroll
      for (int r = 0; r < 4; ++r) {
        const int row = mbase + wr * 64 + mi * 16 + lg * 4 + r;
        const int bi = row >> 11, s = row & (SEQ - 1);
#pragma unroll
        for (int ni = 0; ni < 4; ++ni) {
          const int c = nbase + wc * 64 + ni * 16 + l15;
          const int hh = c & 15, vd = c >> 4;
          Vb[((size_t)((bi * NH + hh) * DK + vd)) * SEQ + s] = f2b(acc[mi][ni][r]);
        }
      }
    }
  } else { // Q or K: rope on (ni, ni+1) pairs
    u16* Ob = (mat == 0) ? Qb : Kb;
    const float qscale = (mat == 0) ? 0.125f * 1.44269504088896f : 1.0f;
#pragma unroll
    for (int ni = 0; ni < 4; ni += 2) {
      const int Xi = (nbase + wc * 64 + ni * 16) >> 5; // 0..31
      const float invf = powf(1000.0f, -(float)Xi / 32.0f);
#pragma unroll
      for (int mi = 0; mi < 4; ++mi) {
#pragma unroll
        for (int r = 0; r < 4; ++r) {
          const int row = mbase + wr * 64 + mi * 16 + lg * 4 + r;
          const int bi = row >> 11, s = row & (SEQ - 1);
          const float pos = (float)tokpos[s];
          const float ang = pos * invf;
          float sn, cs;
          sincosf(ang, &sn, &cs);
          const float x1 = acc[mi][ni][r], x2 = acc[mi][ni + 1][r];
          const float r1 = (x1 * cs - x2 * sn) * qscale;
          const float r2 = (x1 * sn + x2 * cs) * qscale;
          const u32 pk = (u32)f2b(r1) | ((u32)f2b(r2) << 16);
          *(u32*)&Ob[((size_t)((bi * NH + l15) * SEQ + s) << 6) + (Xi << 1)] = pk;
        }
      }
    }
  }
}

// ---------------- flash attention (causal, swapped-operand, in-register softmax) ---
// grid 1024 blocks = 32 q-tiles x 32 heads, remapped so each XCD owns 4 heads
// (KV L2-resident) and heavy q-tiles dispatch first. 256 thr = 4 waves; wave owns
// 16 q rows (q = lane&15 after swapped QK^T -> softmax is lane-local scalars).
// KV tile 64, double-buffered global_load_lds with XOR chunk swizzle.
__global__ __launch_bounds__(256) void flash_attn(
    const u16* __restrict__ Qg, const u16* __restrict__ Kg,
    const u16* __restrict__ VTg, u16* __restrict__ Ag) {
  __shared__ __align__(16) u16 Ks[2][64 * 64];
  __shared__ __align__(16) u16 Vs[2][64 * 64];
  __shared__ __align__(16) u16 Ps[4][16][72];

  // work-id swizzle: id&7 -> XCD slot, 4 heads per XCD, qt descending (heavy first)
  const int id = blockIdx.y * 32 + blockIdx.x;
  const int within = id >> 3;
  const int bh = (id & 7) * 4 + (within & 3);
  const int qt = 31 - (within >> 2);
  const int b = bh >> 4, h = bh & 15;
  const int qbase = qt * 64;

  const size_t hoff = (size_t)bh * SEQ * DK;
  const u16* Qh = Qg + hoff;
  const u16* Kh = Kg + hoff;
  const u16* VTh = VTg + hoff;

  const int t = threadIdx.x;
  const int lane = t & 63, w = t >> 6;
  const int l15 = lane & 15, lg = lane >> 4;
  const int sw = l15 & 7; // read-side XOR

  const int qrow = qbase + w * 16 + l15; // this lane's q row
  const bf16x8 qf0 = *(const bf16x8*)&Qh[(size_t)qrow * DK + lg * 8];
  const bf16x8 qf1 = *(const bf16x8*)&Qh[(size_t)qrow * DK + 32 + lg * 8];

  f32x4 oaccT[4]; // O^T[v = vf*16+lg*4+r][q = l15]
#pragma unroll
  for (int vf = 0; vf < 4; ++vf) {
    f32x4 z = {0.f, 0.f, 0.f, 0.f};
    oaccT[vf] = z;
  }
  float m_r = -1e30f, l_r = 0.0f; // per-lane (per q-row) softmax state

  // staging map: thread t covers LDS bytes [t*16) and [4096 + t*16)
  const int srow = t >> 3;                     // 0..31
  const int sc = ((t & 7) ^ (srow & 7)) * 8;   // swizzled global source chunk

  // prologue: stage tile 0 into buf 0
  gload16(&Kh[(size_t)srow * DK + sc], &Ks[0][t * 8]);
  gload16(&Kh[(size_t)(srow + 32) * DK + sc], &Ks[0][2048 + t * 8]);
  gload16(&VTh[(size_t)srow * SEQ + sc], &Vs[0][t * 8]);
  gload16(&VTh[(size_t)(srow + 32) * SEQ + sc], &Vs[0][2048 + t * 8]);

  for (int kt = 0; kt <= qt; ++kt) {
    const int buf = kt & 1;
    __syncthreads(); // tile kt landed; previous iteration's LDS reads done
    if (kt < qt) {
      const int kb = (kt + 1) * 64;
      gload16(&Kh[(size_t)(kb + srow) * DK + sc], &Ks[buf ^ 1][t * 8]);
      gload16(&Kh[(size_t)(kb + srow + 32) * DK + sc], &Ks[buf ^ 1][2048 + t * 8]);
      gload16(&VTh[(size_t)srow * SEQ + kb + sc], &Vs[buf ^ 1][t * 8]);
      gload16(&VTh[(size_t)(srow + 32) * SEQ + kb + sc], &Vs[buf ^ 1][2048 + t * 8]);
    }
    const int kvbase = kt * 64;

    // S^T = K Q^T : lane holds S[q=qrow][kv = kvbase + f*16 + lg*4 + r]
    f32x4 sT[4];
#pragma unroll
    for (int f = 0; f < 4; ++f) {
      const int row = f * 16 + l15;
      bf16x8 k0 = *(const bf16x8*)&Ks[buf][row * 64 + (lg ^ sw) * 8];
      bf16x8 k1 = *(const bf16x8*)&Ks[buf][row * 64 + ((4 + lg) ^ sw) * 8];
      f32x4 z = {0.f, 0.f, 0.f, 0.f};
      z = __builtin_amdgcn_mfma_f32_16x16x32_bf16(k0, qf0, z, 0, 0, 0);
      z = __builtin_amdgcn_mfma_f32_16x16x32_bf16(k1, qf1, z, 0, 0, 0);
      sT[f] = z;
    }

    if (kt == qt) { // only the diagonal tile needs masking
#pragma unroll
      for (int f = 0; f < 4; ++f)
#pragma unroll
        for (int r = 0; r < 4; ++r) {
          const int kvc = kvbase + f * 16 + lg * 4 + r;
          if (kvc > qrow) sT[f][r] = -1e30f;
        }
    }

    // in-lane row max (16 vals) + 2 cross-lane steps (lg dimension)
    f32x4 mv;
#pragma unroll
    for (int r = 0; r < 4; ++r)
      mv[r] = fmaxf(fmaxf(sT[0][r], sT[1][r]), fmaxf(sT[2][r], sT[3][r]));
    float mx = fmaxf(fmaxf(mv[0], mv[1]), fmaxf(mv[2], mv[3]));
    mx = fmaxf(mx, __shfl_xor(mx, 16));
    mx = fmaxf(mx, __shfl_xor(mx, 32));

    const float mn = fmaxf(m_r, mx);
    const float alpha = exp2f(m_r - mn);
    m_r = mn;
#pragma unroll
    for (int f = 0; f < 4; ++f)
#pragma unroll
      for (int r = 0; r < 4; ++r) sT[f][r] = exp2f(sT[f][r] - mn);

    f32x4 rv;
#pragma unroll
    for (int r = 0; r < 4; ++r) rv[r] = (sT[0][r] + sT[1][r]) + (sT[2][r] + sT[3][r]);
    float rs = (rv[0] + rv[1]) + (rv[2] + rv[3]);
    rs += __shfl_xor(rs, 16);
    rs += __shfl_xor(rs, 32);
    l_r = l_r * alpha + rs;

#pragma unroll
    for (int vf = 0; vf < 4; ++vf)
#pragma unroll
      for (int r = 0; r < 4; ++r) oaccT[vf][r] *= alpha;

    // P row (q=l15) -> LDS: 4x ds_write_b64, contiguous kv runs
#pragma unroll
    for (int f = 0; f < 4; ++f) {
      uint2 pkv;
      pkv.x = (u32)f2b(sT[f][0]) | ((u32)f2b(sT[f][1]) << 16);
      pkv.y = (u32)f2b(sT[f][2]) | ((u32)f2b(sT[f][3]) << 16);
      *(uint2*)&Ps[w][l15][f * 16 + lg * 4] = pkv;
    }

    // O^T += V^T P^T : A = V^T frag, B = P^T frag (2x ds_read_b128 for P)
#pragma unroll
    for (int c = 0; c < 2; ++c) {
      const bf16x8 pb = *(const bf16x8*)&Ps[w][l15][c * 32 + lg * 8];
#pragma unroll
      for (int vf = 0; vf < 4; ++vf) {
        const bf16x8 va =
            *(const bf16x8*)&Vs[buf][(vf * 16 + l15) * 64 + ((c * 4 + lg) ^ sw) * 8];
        oaccT[vf] = __builtin_amdgcn_mfma_f32_16x16x32_bf16(va, pb, oaccT[vf], 0, 0, 0);
      }
    }
  }

  // normalize + write [B,S,D] bf16: d = h*64 + v, packed 4-wide
  const float inv = 1.0f / l_r;
  const size_t base = ((size_t)(b * SEQ + qrow)) * DMODEL + h * DK;
#pragma unroll
  for (int vf = 0; vf < 4; ++vf) {
    uint2 ov;
    ov.x = (u32)f2b(oaccT[vf][0] * inv) | ((u32)f2b(oaccT[vf][1] * inv) << 16);
    ov.y = (u32)f2b(oaccT[vf][2] * inv) | ((u32)f2b(oaccT[vf][3] * inv) << 16);
    *(uint2*)&Ag[base + vf * 16 + lg * 4] = ov;
  }
}

// ---------------- output projection: d_out = Ab * Wot^T (fp32 out) ----------------
__global__ __launch_bounds__(256) void gemm_out(const u16* __restrict__ Ab,
                                                const u16* __restrict__ Wotb,
                                                float* __restrict__ Co) {
  __shared__ __align__(16) u16 As[128 * 32];
  __shared__ __align__(16) u16 Bs[128 * 32];
  const int mbase = blockIdx.x * 128, nbase = blockIdx.y * 128;

  f32x4 acc[4][4];
#pragma unroll
  for (int mi = 0; mi < 4; ++mi)
#pragma unroll
    for (int ni = 0; ni < 4; ++ni) {
      f32x4 z = {0.f, 0.f, 0.f, 0.f};
      acc[mi][ni] = z;
    }

  gemm_core(Ab, Wotb, mbase, nbase, As, Bs, acc);

  const int t = threadIdx.x;
  const int lane = t & 63, w = t >> 6;
  const int wr = w >> 1, wc = w & 1;
  const int l15 = lane & 15, lg = lane >> 4;
#pragma unroll
  for (int mi = 0; mi < 4; ++mi) {
#pragma unroll
    for (int r = 0; r < 4; ++r) {
      const int row = mbase + wr * 64 + mi * 16 + lg * 4 + r;
#pragma unroll
      for (int ni = 0; ni < 4; ++ni) {
        const int c = nbase + wc * 64 + ni * 16 + l15;
        Co[(size_t)row * DMODEL + c] = acc[mi][ni][r];
      }
    }
  }
}

extern "C" void kernel_launch(void* const* d_in, const int* in_sizes, int n_in,
                              void* d_out, int out_size, void* d_ws, size_t ws_size,
                              hipStream_t stream) {
  const float* X = (const float*)d_in[0];
  const float* Wq = (const float*)d_in[1];
  const float* Wk = (const float*)d_in[2];
  const float* Wv = (const float*)d_in[3];
  const float* Wo = (const float*)d_in[4];
  const int* tokpos = (const int*)d_in[5];
  float* out = (float*)d_out;

  u16* p = (u16*)d_ws;
  u16* Xb = p;   p += (size_t)MTOT * DMODEL;        // 4M el
  u16* Wqb = p;  p += (size_t)DMODEL * DMODEL;      // 1M el
  u16* Wkb = p;  p += (size_t)DMODEL * DMODEL;
  u16* Wvb = p;  p += (size_t)DMODEL * DMODEL;
  u16* Wotb = p; p += (size_t)DMODEL * DMODEL;
  u16* Qb = p;   p += (size_t)BATCH * NH * SEQ * DK; // 4M el
  u16* Kb = p;   p += (size_t)BATCH * NH * SEQ * DK;
  u16* Vb = p;   p += (size_t)BATCH * NH * SEQ * DK; // holds V^T [bh][vd][s]
  u16* Ab = Xb; // X is dead after QKV projection; reuse for attention output

  cvt_bf16<<<4096, 256, 0, stream>>>(X, Xb, (MTOT * DMODEL) / 4);
  cvt_bf16<<<1024, 256, 0, stream>>>(Wq, Wqb, (DMODEL * DMODEL) / 4);
  cvt_bf16<<<1024, 256, 0, stream>>>(Wk, Wkb, (DMODEL * DMODEL) / 4);
  cvt_bf16<<<1024, 256, 0, stream>>>(Wv, Wvb, (DMODEL * DMODEL) / 4);
  transpose_wo<<<dim3(32, 32), 256, 0, stream>>>(Wo, Wotb);

  gemm_qkv<<<dim3(32, 24), 256, 0, stream>>>(Xb, Wqb, Wkb, Wvb, Qb, Kb, Vb, tokpos);
  flash_attn<<<dim3(32, 32), 256, 0, stream>>>(Qb, Kb, Vb, Ab);
  gemm_out<<<dim3(32, 8), 256, 0, stream>>>(Ab, Wotb, out);
}

// Round 5
// 145.707 us; speedup vs baseline: 1.7357x; 1.0868x over previous
//
#include <hip/hip_runtime.h>

typedef unsigned short u16;
typedef unsigned int u32;
typedef __bf16 bf16x8 __attribute__((ext_vector_type(8)));
typedef float f32x4 __attribute__((ext_vector_type(4)));

#define SEQ 2048
#define DMODEL 1024
#define NH 16
#define DK 64
#define BATCH 2
#define MTOT (BATCH * SEQ) // 4096

__device__ __forceinline__ u16 f2b(float f) {
  u32 u = __float_as_uint(f);
  u += 0x7fffu + ((u >> 16) & 1u);
  return (u16)(u >> 16);
}

__device__ __forceinline__ void gload16(const void* g, void* l) {
  __builtin_amdgcn_global_load_lds((const __attribute__((address_space(1))) u32*)g,
                                   (__attribute__((address_space(3))) u32*)l, 16, 0, 0);
}

// ---------------- fp32 -> bf16 convert (vectorized) ----------------
__global__ __launch_bounds__(256) void cvt_bf16(const float* __restrict__ in,
                                                u16* __restrict__ out, int n4) {
  int i = blockIdx.x * 256 + threadIdx.x;
  if (i < n4) {
    float4 v = ((const float4*)in)[i];
    uint2 o;
    o.x = (u32)f2b(v.x) | ((u32)f2b(v.y) << 16);
    o.y = (u32)f2b(v.z) | ((u32)f2b(v.w) << 16);
    ((uint2*)out)[i] = o;
  }
}

// ---------------- RoPE cos/sin table: tab[s*32+Xi] = (cos, sin) ----------------
__global__ __launch_bounds__(256) void rope_tab_k(const int* __restrict__ tokpos,
                                                  float2* __restrict__ tab) {
  const int i = blockIdx.x * 256 + threadIdx.x; // < SEQ*32
  const int s = i >> 5, Xi = i & 31;
  const float invf = powf(1000.0f, -(float)Xi / 32.0f);
  const float ang = (float)tokpos[s] * invf;
  float sn, cs;
  sincosf(ang, &sn, &cs);
  tab[i] = make_float2(cs, sn);
}

// ---------------- Wo transpose + convert: wot[e][d] = wo[d][e] ----------------
__global__ __launch_bounds__(256) void transpose_wo(const float* __restrict__ wo,
                                                    u16* __restrict__ wot) {
  __shared__ float tile[32][33];
  const int bx = blockIdx.x * 32; // e block
  const int by = blockIdx.y * 32; // d block
  const int tx = threadIdx.x & 31, ty = threadIdx.x >> 5;
  for (int j = ty; j < 32; j += 8)
    tile[j][tx] = wo[(size_t)(by + j) * DMODEL + bx + tx];
  __syncthreads();
  for (int j = ty; j < 32; j += 8)
    wot[(size_t)(bx + j) * DMODEL + by + tx] = f2b(tile[tx][j]);
}

// ---------------- shared GEMM mainloop (BK=64, XOR-swizzled LDS) ----------------
// C[BM x 128] = A[M,K] * Bt[N,K]^T, BM = MI*32. 4 waves: wr = w>>1 (BM/2 rows),
// wc = w&1 (64 cols). LDS[row][chunk] = G[row][chunk ^ (row&7)] (16B chunks),
// staged via per-lane pre-swizzled global source; reads apply the same XOR.
template <int MI>
__device__ __forceinline__ void gemm_core(const u16* __restrict__ A,
                                          const u16* __restrict__ Bt,
                                          int mbase, int nbase,
                                          u16* As, u16* Bs, f32x4 acc[MI][4]) {
  const int t = threadIdx.x;
  const int lane = t & 63, w = t >> 6;
  const int wr = w >> 1, wc = w & 1;
  const int l15 = lane & 15, lg = lane >> 4;
  const int srow = t >> 3;              // 0..31
  const int sch = (t & 7) ^ (srow & 7); // swizzled source chunk
  const int rsw = l15 & 7;              // read-side XOR (row&7 == l15&7)

  for (int kb = 0; kb < DMODEL; kb += 64) {
#pragma unroll
    for (int j = 0; j < MI; ++j)
      gload16(&A[(size_t)(mbase + srow + 32 * j) * DMODEL + kb + sch * 8],
              &As[j * 2048 + t * 8]);
#pragma unroll
    for (int j = 0; j < 4; ++j)
      gload16(&Bt[(size_t)(nbase + srow + 32 * j) * DMODEL + kb + sch * 8],
              &Bs[j * 2048 + t * 8]);
    __syncthreads();
#pragma unroll
    for (int kk = 0; kk < 2; ++kk) {
      bf16x8 af[MI], bfr[4];
#pragma unroll
      for (int mi = 0; mi < MI; ++mi) {
        const int row = wr * (MI * 16) + mi * 16 + l15;
        af[mi] = *(const bf16x8*)&As[row * 64 + (((kk * 4 + lg) ^ rsw) * 8)];
      }
#pragma unroll
      for (int ni = 0; ni < 4; ++ni) {
        const int row = wc * 64 + ni * 16 + l15;
        bfr[ni] = *(const bf16x8*)&Bs[row * 64 + (((kk * 4 + lg) ^ rsw) * 8)];
      }
#pragma unroll
      for (int mi = 0; mi < MI; ++mi)
#pragma unroll
        for (int ni = 0; ni < 4; ++ni)
          acc[mi][ni] =
              __builtin_amdgcn_mfma_f32_16x16x32_bf16(af[mi], bfr[ni], acc[mi][ni], 0, 0, 0);
    }
    __syncthreads();
  }
}

// ---------------- fused QKV projection + RoPE epilogue (table-based) ----------------
// Q gets 0.125*log2(e) folded in (attention scale + exp2-domain softmax).
// V is written TRANSPOSED per head: Vb[(bh*DK + vd)*SEQ + s].
__global__ __launch_bounds__(256) void gemm_qkv(
    const u16* __restrict__ Xb, const u16* __restrict__ Wqb,
    const u16* __restrict__ Wkb, const u16* __restrict__ Wvb,
    u16* __restrict__ Qb, u16* __restrict__ Kb, u16* __restrict__ Vb,
    const float2* __restrict__ tab) {
  __shared__ __align__(16) u16 As[128 * 64];
  __shared__ __align__(16) u16 Bs[128 * 64];

  const int mat = blockIdx.y >> 3;
  const int nbase = (blockIdx.y & 7) * 128;
  const int mbase = blockIdx.x * 128;
  const u16* Bt = (mat == 0) ? Wqb : ((mat == 1) ? Wkb : Wvb);

  f32x4 acc[4][4];
#pragma unroll
  for (int mi = 0; mi < 4; ++mi)
#pragma unroll
    for (int ni = 0; ni < 4; ++ni) {
      f32x4 z = {0.f, 0.f, 0.f, 0.f};
      acc[mi][ni] = z;
    }

  gemm_core<4>(Xb, Bt, mbase, nbase, As, Bs, acc);

  const int t = threadIdx.x;
  const int lane = t & 63, w = t >> 6;
  const int wr = w >> 1, wc = w & 1;
  const int l15 = lane & 15, lg = lane >> 4;

  if (mat == 2) { // V: no rope, write V^T per head [B,H,64,S]
#pragma unroll
    for (int mi = 0; mi < 4; ++mi) {
#pragma unroll
      for (int r = 0; r < 4; ++r) {
        const int row = mbase + wr * 64 + mi * 16 + lg * 4 + r;
        const int bi = row >> 11, s = row & (SEQ - 1);
#pragma unroll
        for (int ni = 0; ni < 4; ++ni) {
          const int c = nbase + wc * 64 + ni * 16 + l15;
          const int hh = c & 15, vd = c >> 4;
          Vb[((size_t)((bi * NH + hh) * DK + vd)) * SEQ + s] = f2b(acc[mi][ni][r]);
        }
      }
    }
  } else { // Q or K: rope on (ni, ni+1) pairs, cos/sin from table
    u16* Ob = (mat == 0) ? Qb : Kb;
    const float qscale = (mat == 0) ? 0.125f * 1.44269504088896f : 1.0f;
#pragma unroll
    for (int ni = 0; ni < 4; ni += 2) {
      const int Xi = (nbase + wc * 64 + ni * 16) >> 5; // 0..31, uniform per frag
#pragma unroll
      for (int mi = 0; mi < 4; ++mi) {
#pragma unroll
        for (int r = 0; r < 4; ++r) {
          const int row = mbase + wr * 64 + mi * 16 + lg * 4 + r;
          const int bi = row >> 11, s = row & (SEQ - 1);
          const float2 ct = tab[(s << 5) + Xi]; // broadcast across 16 lanes
          const float x1 = acc[mi][ni][r], x2 = acc[mi][ni + 1][r];
          const float r1 = (x1 * ct.x - x2 * ct.y) * qscale;
          const float r2 = (x1 * ct.y + x2 * ct.x) * qscale;
          const u32 pk = (u32)f2b(r1) | ((u32)f2b(r2) << 16);
          *(u32*)&Ob[((size_t)((bi * NH + l15) * SEQ + s) << 6) + (Xi << 1)] = pk;
        }
      }
    }
  }
}

// ---------------- flash attention (causal, swapped-operand, in-register softmax) ---
// grid 1024 blocks = 32 q-tiles x 32 heads, remapped so each XCD owns 4 heads
// (KV L2-resident) and heavy q-tiles dispatch first. 256 thr = 4 waves; wave owns
// 16 q rows (q = lane&15 after swapped QK^T -> softmax is lane-local scalars).
// KV tile 64, double-buffered global_load_lds with XOR chunk swizzle.
__global__ __launch_bounds__(256) void flash_attn(
    const u16* __restrict__ Qg, const u16* __restrict__ Kg,
    const u16* __restrict__ VTg, u16* __restrict__ Ag) {
  __shared__ __align__(16) u16 Ks[2][64 * 64];
  __shared__ __align__(16) u16 Vs[2][64 * 64];
  __shared__ __align__(16) u16 Ps[4][16][72];

  // work-id swizzle: id&7 -> XCD slot, 4 heads per XCD, qt descending (heavy first)
  const int id = blockIdx.y * 32 + blockIdx.x;
  const int within = id >> 3;
  const int bh = (id & 7) * 4 + (within & 3);
  const int qt = 31 - (within >> 2);
  const int b = bh >> 4, h = bh & 15;
  const int qbase = qt * 64;

  const size_t hoff = (size_t)bh * SEQ * DK;
  const u16* Qh = Qg + hoff;
  const u16* Kh = Kg + hoff;
  const u16* VTh = VTg + hoff;

  const int t = threadIdx.x;
  const int lane = t & 63, w = t >> 6;
  const int l15 = lane & 15, lg = lane >> 4;
  const int sw = l15 & 7; // read-side XOR

  const int qrow = qbase + w * 16 + l15; // this lane's q row
  const bf16x8 qf0 = *(const bf16x8*)&Qh[(size_t)qrow * DK + lg * 8];
  const bf16x8 qf1 = *(const bf16x8*)&Qh[(size_t)qrow * DK + 32 + lg * 8];

  f32x4 oaccT[4]; // O^T[v = vf*16+lg*4+r][q = l15]
#pragma unroll
  for (int vf = 0; vf < 4; ++vf) {
    f32x4 z = {0.f, 0.f, 0.f, 0.f};
    oaccT[vf] = z;
  }
  float m_r = -1e30f, l_r = 0.0f; // per-lane (per q-row) softmax state

  // staging map: thread t covers LDS bytes [t*16) and [4096 + t*16)
  const int srow = t >> 3;                     // 0..31
  const int sc = ((t & 7) ^ (srow & 7)) * 8;   // swizzled global source chunk

  // prologue: stage tile 0 into buf 0
  gload16(&Kh[(size_t)srow * DK + sc], &Ks[0][t * 8]);
  gload16(&Kh[(size_t)(srow + 32) * DK + sc], &Ks[0][2048 + t * 8]);
  gload16(&VTh[(size_t)srow * SEQ + sc], &Vs[0][t * 8]);
  gload16(&VTh[(size_t)(srow + 32) * SEQ + sc], &Vs[0][2048 + t * 8]);

  for (int kt = 0; kt <= qt; ++kt) {
    const int buf = kt & 1;
    __syncthreads(); // tile kt landed; previous iteration's LDS reads done
    if (kt < qt) {
      const int kb = (kt + 1) * 64;
      gload16(&Kh[(size_t)(kb + srow) * DK + sc], &Ks[buf ^ 1][t * 8]);
      gload16(&Kh[(size_t)(kb + srow + 32) * DK + sc], &Ks[buf ^ 1][2048 + t * 8]);
      gload16(&VTh[(size_t)srow * SEQ + kb + sc], &Vs[buf ^ 1][t * 8]);
      gload16(&VTh[(size_t)(srow + 32) * SEQ + kb + sc], &Vs[buf ^ 1][2048 + t * 8]);
    }
    const int kvbase = kt * 64;

    // S^T = K Q^T : lane holds S[q=qrow][kv = kvbase + f*16 + lg*4 + r]
    f32x4 sT[4];
#pragma unroll
    for (int f = 0; f < 4; ++f) {
      const int row = f * 16 + l15;
      bf16x8 k0 = *(const bf16x8*)&Ks[buf][row * 64 + (lg ^ sw) * 8];
      bf16x8 k1 = *(const bf16x8*)&Ks[buf][row * 64 + ((4 + lg) ^ sw) * 8];
      f32x4 z = {0.f, 0.f, 0.f, 0.f};
      z = __builtin_amdgcn_mfma_f32_16x16x32_bf16(k0, qf0, z, 0, 0, 0);
      z = __builtin_amdgcn_mfma_f32_16x16x32_bf16(k1, qf1, z, 0, 0, 0);
      sT[f] = z;
    }

    if (kt == qt) { // only the diagonal tile needs masking
#pragma unroll
      for (int f = 0; f < 4; ++f)
#pragma unroll
        for (int r = 0; r < 4; ++r) {
          const int kvc = kvbase + f * 16 + lg * 4 + r;
          if (kvc > qrow) sT[f][r] = -1e30f;
        }
    }

    // in-lane row max (16 vals) + 2 cross-lane steps (lg dimension)
    f32x4 mv;
#pragma unroll
    for (int r = 0; r < 4; ++r)
      mv[r] = fmaxf(fmaxf(sT[0][r], sT[1][r]), fmaxf(sT[2][r], sT[3][r]));
    float mx = fmaxf(fmaxf(mv[0], mv[1]), fmaxf(mv[2], mv[3]));
    mx = fmaxf(mx, __shfl_xor(mx, 16));
    mx = fmaxf(mx, __shfl_xor(mx, 32));

    const float mn = fmaxf(m_r, mx);
    const float alpha = exp2f(m_r - mn);
    m_r = mn;
#pragma unroll
    for (int f = 0; f < 4; ++f)
#pragma unroll
      for (int r = 0; r < 4; ++r) sT[f][r] = exp2f(sT[f][r] - mn);

    f32x4 rv;
#pragma unroll
    for (int r = 0; r < 4; ++r) rv[r] = (sT[0][r] + sT[1][r]) + (sT[2][r] + sT[3][r]);
    float rs = (rv[0] + rv[1]) + (rv[2] + rv[3]);
    rs += __shfl_xor(rs, 16);
    rs += __shfl_xor(rs, 32);
    l_r = l_r * alpha + rs;

#pragma unroll
    for (int vf = 0; vf < 4; ++vf)
#pragma unroll
      for (int r = 0; r < 4; ++r) oaccT[vf][r] *= alpha;

    // P row (q=l15) -> LDS: 4x ds_write_b64, contiguous kv runs
#pragma unroll
    for (int f = 0; f < 4; ++f) {
      uint2 pkv;
      pkv.x = (u32)f2b(sT[f][0]) | ((u32)f2b(sT[f][1]) << 16);
      pkv.y = (u32)f2b(sT[f][2]) | ((u32)f2b(sT[f][3]) << 16);
      *(uint2*)&Ps[w][l15][f * 16 + lg * 4] = pkv;
    }

    // O^T += V^T P^T : A = V^T frag, B = P^T frag (2x ds_read_b128 for P)
#pragma unroll
    for (int c = 0; c < 2; ++c) {
      const bf16x8 pb = *(const bf16x8*)&Ps[w][l15][c * 32 + lg * 8];
#pragma unroll
      for (int vf = 0; vf < 4; ++vf) {
        const bf16x8 va =
            *(const bf16x8*)&Vs[buf][(vf * 16 + l15) * 64 + ((c * 4 + lg) ^ sw) * 8];
        oaccT[vf] = __builtin_amdgcn_mfma_f32_16x16x32_bf16(va, pb, oaccT[vf], 0, 0, 0);
      }
    }
  }

  // normalize + write [B,S,D] bf16: d = h*64 + v, packed 4-wide
  const float inv = 1.0f / l_r;
  const size_t base = ((size_t)(b * SEQ + qrow)) * DMODEL + h * DK;
#pragma unroll
  for (int vf = 0; vf < 4; ++vf) {
    uint2 ov;
    ov.x = (u32)f2b(oaccT[vf][0] * inv) | ((u32)f2b(oaccT[vf][1] * inv) << 16);
    ov.y = (u32)f2b(oaccT[vf][2] * inv) | ((u32)f2b(oaccT[vf][3] * inv) << 16);
    *(uint2*)&Ag[base + vf * 16 + lg * 4] = ov;
  }
}

// ---------------- output projection: d_out = Ab * Wot^T (fp32 out) ----------------
// 64x128 tile (MI=2), grid (64, 8) = 512 blocks = 2 blocks/CU for overlap.
__global__ __launch_bounds__(256) void gemm_out(const u16* __restrict__ Ab,
                                                const u16* __restrict__ Wotb,
                                                float* __restrict__ Co) {
  __shared__ __align__(16) u16 As[64 * 64];
  __shared__ __align__(16) u16 Bs[128 * 64];
  const int mbase = blockIdx.x * 64, nbase = blockIdx.y * 128;

  f32x4 acc[2][4];
#pragma unroll
  for (int mi = 0; mi < 2; ++mi)
#pragma unroll
    for (int ni = 0; ni < 4; ++ni) {
      f32x4 z = {0.f, 0.f, 0.f, 0.f};
      acc[mi][ni] = z;
    }

  gemm_core<2>(Ab, Wotb, mbase, nbase, As, Bs, acc);

  const int t = threadIdx.x;
  const int lane = t & 63, w = t >> 6;
  const int wr = w >> 1, wc = w & 1;
  const int l15 = lane & 15, lg = lane >> 4;
#pragma unroll
  for (int mi = 0; mi < 2; ++mi) {
#pragma unroll
    for (int r = 0; r < 4; ++r) {
      const int row = mbase + wr * 32 + mi * 16 + lg * 4 + r;
#pragma unroll
      for (int ni = 0; ni < 4; ++ni) {
        const int c = nbase + wc * 64 + ni * 16 + l15;
        Co[(size_t)row * DMODEL + c] = acc[mi][ni][r];
      }
    }
  }
}

extern "C" void kernel_launch(void* const* d_in, const int* in_sizes, int n_in,
                              void* d_out, int out_size, void* d_ws, size_t ws_size,
                              hipStream_t stream) {
  const float* X = (const float*)d_in[0];
  const float* Wq = (const float*)d_in[1];
  const float* Wk = (const float*)d_in[2];
  const float* Wv = (const float*)d_in[3];
  const float* Wo = (const float*)d_in[4];
  const int* tokpos = (const int*)d_in[5];
  float* out = (float*)d_out;

  u16* p = (u16*)d_ws;
  u16* Xb = p;   p += (size_t)MTOT * DMODEL;        // 4M el
  u16* Wqb = p;  p += (size_t)DMODEL * DMODEL;      // 1M el
  u16* Wkb = p;  p += (size_t)DMODEL * DMODEL;
  u16* Wvb = p;  p += (size_t)DMODEL * DMODEL;
  u16* Wotb = p; p += (size_t)DMODEL * DMODEL;
  u16* Qb = p;   p += (size_t)BATCH * NH * SEQ * DK; // 4M el
  u16* Kb = p;   p += (size_t)BATCH * NH * SEQ * DK;
  u16* Vb = p;   p += (size_t)BATCH * NH * SEQ * DK; // holds V^T [bh][vd][s]
  float2* tab = (float2*)(p + 512);                  // 512 KB rope table (aligned)
  u16* Ab = Xb; // X is dead after QKV projection; reuse for attention output

  cvt_bf16<<<4096, 256, 0, stream>>>(X, Xb, (MTOT * DMODEL) / 4);
  cvt_bf16<<<1024, 256, 0, stream>>>(Wq, Wqb, (DMODEL * DMODEL) / 4);
  cvt_bf16<<<1024, 256, 0, stream>>>(Wk, Wkb, (DMODEL * DMODEL) / 4);
  cvt_bf16<<<1024, 256, 0, stream>>>(Wv, Wvb, (DMODEL * DMODEL) / 4);
  transpose_wo<<<dim3(32, 32), 256, 0, stream>>>(Wo, Wotb);
  rope_tab_k<<<(SEQ * 32) / 256, 256, 0, stream>>>(tokpos, tab);

  gemm_qkv<<<dim3(32, 24), 256, 0, stream>>>(Xb, Wqb, Wkb, Wvb, Qb, Kb, Vb, tab);
  flash_attn<<<dim3(32, 32), 256, 0, stream>>>(Qb, Kb, Vb, Ab);
  gemm_out<<<dim3(64, 8), 256, 0, stream>>>(Ab, Wotb, out);
}